// Round 6
// baseline (280.792 us; speedup 1.0000x reference)
//
#include <hip/hip_runtime.h>
#include <hip/hip_bf16.h>

#define B_ 4096
#define D_ 1024
#define H_ 8192
#define O_ 1000
#define K2 2048          // physical packed K ([hi|lo])
#define NT 48            // logical K-tiles: 3072 / 64
#define NITER (NT / 2)

typedef __attribute__((ext_vector_type(8))) short short8;
typedef __attribute__((ext_vector_type(4))) short short4v;
typedef __attribute__((ext_vector_type(4))) float f32x4;

union BF4 { __hip_bfloat16 b[4]; short4v s; };

__device__ __forceinline__ void gload16(void* ldsp, const void* g) {
  __builtin_amdgcn_global_load_lds(
      (const __attribute__((address_space(1))) unsigned int*)g,
      (__attribute__((address_space(3))) unsigned int*)ldsp, 16, 0, 0);
}

// K-tile T -> column offset in packed [hi(0..1023)|lo(1024..2047)] rows.
// Interleaved bf16x3: T = 3t+r: r0 = xh*wh, r1 = xl*wh, r2 = xh*wl.
__device__ __forceinline__ int aoff_(int T) {
  const int t = T / 3, r = T - 3 * t;
  return (r == 1 ? 1024 : 0) + t * 64;
}
__device__ __forceinline__ int boff_(int T) {
  const int t = T / 3, r = T - 3 * t;
  return (r == 2 ? 1024 : 0) + t * 64;
}

// ---- merged split: fp32 -> [hi|lo] bf16 + sum-of-squares + keys init ----
__global__ __launch_bounds__(256) void split_all_kernel(
    const float* __restrict__ x, const float* __restrict__ w,
    __hip_bfloat16* __restrict__ Ap, __hip_bfloat16* __restrict__ Bp,
    float* __restrict__ xsq, float* __restrict__ wsq,
    unsigned long long* __restrict__ keys)
{
  const int r = blockIdx.x;
  const int t = threadIdx.x;
  const float* src;
  __hip_bfloat16* dst;
  float* sq;
  if (r < B_) {
    src = x + (size_t)r * D_; dst = Ap + (size_t)r * K2; sq = xsq + r;
    if (t == 0) keys[r] = ~0ULL;
  } else {
    const int rr = r - B_;
    src = w + (size_t)rr * D_; dst = Bp + (size_t)rr * K2; sq = wsq + rr;
  }
  const float4 v = ((const float4*)src)[t];
  float ss = v.x * v.x + v.y * v.y + v.z * v.z + v.w * v.w;

  BF4 Hh, Ll;
  const float e[4] = {v.x, v.y, v.z, v.w};
#pragma unroll
  for (int i = 0; i < 4; ++i) {
    __hip_bfloat16 h = __float2bfloat16(e[i]);
    Hh.b[i] = h;
    Ll.b[i] = __float2bfloat16(e[i] - __bfloat162float(h));
  }
  *(short4v*)(dst + t * 4) = Hh.s;
  *(short4v*)(dst + 1024 + t * 4) = Ll.s;

#pragma unroll
  for (int o = 32; o > 0; o >>= 1) ss += __shfl_down(ss, o);
  __shared__ float wsum[4];
  if ((t & 63) == 0) wsum[t >> 6] = ss;
  __syncthreads();
  if (t == 0) *sq = (wsum[0] + wsum[1]) + (wsum[2] + wsum[3]);
}

// ---- 256x256 GEMM, 8-phase, uniform 1-stage/phase, all-counted vmcnt(8) ----
// LDS: dbuf d: A0 rows0-127 @d+0, A1 @d+16K, B0 @d+32K, B1 @d+48K.
// 128B rows; phys 16B-unit = logical ^ (row&7) (applied via pre-swizzled src).
// Quadrants (mh,nh): wave wm reads A rows mh*128+wm*64..+64 (one half per mh);
// wave wn reads B cols nh*128+wn*32..+32. Each half LDS-read in EXACTLY one
// phase -> stage schedule: ph0:A1(b) ph1:A0(a+2) ph2:B0(a+2) ph3:B1(a+2)
// ph4:A1(a+2) ph5:A0(b+2) ph6:B0(b+2) ph7:B1(b+2). Lead 5-6 phases.
// Gates vmcnt(8) (= allow 4 newest phases' stages) at end of ph0,2,3,4,6,7.
// WAR: stage at ph_p writes a half whose reads drained before MFMA(ph_{p-2..p-1})
// and were certified by that phase's barrier.

#define BAR() do { asm volatile("" ::: "memory"); \
                   __builtin_amdgcn_s_barrier(); \
                   asm volatile("" ::: "memory"); } while (0)
#define GATE8() asm volatile("s_waitcnt vmcnt(8)" ::: "memory")

#define STAGE(P, prow, T, isB, h) do { if ((T) < NT) { \
    const int koff_ = (isB) ? boff_(T) : aoff_(T); \
    const __hip_bfloat16* s_ = (P) + (size_t)((prow) + (h)*128 + wid*16 + srow) * K2 + koff_ + sunit * 8; \
    char* d_ = lds + ((T)&1)*65536 + (isB)*32768 + (h)*16384 + wid*2048 + lane*16; \
    gload16(d_, s_); gload16(d_ + 1024, s_ + 8*K2); } } while (0)

// 8 reads: A-frags of m-half mh (4 m x 2 kk)
#define READ_A(dst, db, mh) do { \
    const char* p_ = lds + (db) + (mh)*16384 + (wm*64 + cc)*128; \
    _Pragma("unroll") for (int m_ = 0; m_ < 4; ++m_) { \
      dst[2*m_]   = *(const short8*)(p_ + m_*2048 + kof0); \
      dst[2*m_+1] = *(const short8*)(p_ + m_*2048 + kof1); } } while (0)

// 4 reads: B-frags of n-half nh (2 n x 2 kk)
#define READ_B(dst, db, nh) do { \
    const char* p_ = lds + (db) + 32768 + (nh)*16384 + (wn*32 + cc)*128; \
    _Pragma("unroll") for (int n_ = 0; n_ < 2; ++n_) { \
      dst[2*n_]   = *(const short8*)(p_ + n_*2048 + kof0); \
      dst[2*n_+1] = *(const short8*)(p_ + n_*2048 + kof1); } } while (0)

#define MM(mh, nh, AF, BF) do { \
    __builtin_amdgcn_s_setprio(1); \
    _Pragma("unroll") for (int m_ = 0; m_ < 4; ++m_) \
    _Pragma("unroll") for (int n_ = 0; n_ < 2; ++n_) \
    _Pragma("unroll") for (int kk = 0; kk < 2; ++kk) \
      acc[(mh)*4+m_][(nh)*2+n_] = __builtin_amdgcn_mfma_f32_16x16x32_bf16( \
          AF[2*m_+kk], BF[2*n_+kk], acc[(mh)*4+m_][(nh)*2+n_], 0, 0, 0); \
    __builtin_amdgcn_s_setprio(0); } while (0)

__global__ __launch_bounds__(512, 2) void gemm_argmin_kernel(
    const __hip_bfloat16* __restrict__ Ap, const __hip_bfloat16* __restrict__ Bp,
    const float* __restrict__ xsq, const float* __restrict__ wsq,
    unsigned long long* __restrict__ keys)
{
  __shared__ char lds[131072];

  const int t = threadIdx.x;
  // XCD-aware: square 8x8 tile-chunk per XCD (r4-proven).
  const int id = blockIdx.x;
  const int xcd = id & 7;
  const int r_ = id >> 3;
  const int by = (xcd >> 2) * 8 + (r_ >> 3);
  const int bx = (xcd & 3) * 8 + (r_ & 7);
  const int brow = by * 256, bcol = bx * 256;

  const int lane = t & 63, wid = t >> 6;
  const int wm = wid >> 2, wn = wid & 3;
  const int cc = lane & 15, q = lane >> 4, sw = lane & 7;
  const int kof0 = (q ^ sw) * 16;
  const int kof1 = ((4 + q) ^ sw) * 16;

  const int srow = lane >> 3;
  const int sunit = (lane & 7) ^ srow;

  f32x4 acc[8][4] = {};
  short8 aF0[8], aF1[8], bF0[4], bF1[4];

  // Prologue (ledger order, oldest->newest): A0(0) B0(0) B1(0) A1(0) A0(1) B0(1) B1(1)
  STAGE(Ap, brow, 0, 0, 0);
  STAGE(Bp, bcol, 0, 1, 0);
  STAGE(Bp, bcol, 0, 1, 1);
  STAGE(Ap, brow, 0, 0, 1);
  STAGE(Ap, brow, 1, 0, 0);
  STAGE(Bp, bcol, 1, 1, 0);
  STAGE(Bp, bcol, 1, 1, 1);
  GATE8();           // 14 outstanding -> oldest 6 landed: A0(0),B0(0),B1(0)
  BAR();
  READ_A(aF0, 0, 0); // tile0 A-half0
  READ_B(bF0, 0, 0); // tile0 B-half0

  for (int it = 0; it < NITER; ++it) {
    const int a = 2 * it, b = a + 1;
    // ph0: MFMA a(mh0,nh0); read B1q(a); stage A1(b)
    READ_B(bF1, 0, 1);
    STAGE(Ap, brow, b, 0, 1);
    MM(0, 0, aF0, bF0);
    GATE8(); BAR();
    // ph1: MFMA a(mh0,nh1); read A1q(a); stage A0(a+2)
    READ_A(aF1, 0, 1);
    STAGE(Ap, brow, a + 2, 0, 0);
    MM(0, 1, aF0, bF1);
    BAR();
    // ph2: MFMA a(mh1,nh0) [bF0 reused]; stage B0(a+2)
    STAGE(Bp, bcol, a + 2, 1, 0);
    MM(1, 0, aF1, bF0);
    GATE8(); BAR();
    // ph3: MFMA a(mh1,nh1) [bF1 reused]; read A0q(b)+B0q(b); stage B1(a+2)
    READ_A(aF0, 65536, 0);
    READ_B(bF0, 65536, 0);
    STAGE(Bp, bcol, a + 2, 1, 1);
    MM(1, 1, aF1, bF1);
    GATE8(); BAR();
    // ph4: MFMA b(mh0,nh0); read B1q(b); stage A1(a+2)
    READ_B(bF1, 65536, 1);
    STAGE(Ap, brow, a + 2, 0, 1);
    MM(0, 0, aF0, bF0);
    GATE8(); BAR();
    // ph5: MFMA b(mh0,nh1); read A1q(b); stage A0(b+2)
    READ_A(aF1, 65536, 1);
    STAGE(Ap, brow, b + 2, 0, 0);
    MM(0, 1, aF0, bF1);
    BAR();
    // ph6: MFMA b(mh1,nh0); stage B0(b+2)
    STAGE(Bp, bcol, b + 2, 1, 0);
    MM(1, 0, aF1, bF0);
    GATE8(); BAR();
    // ph7: MFMA b(mh1,nh1); read A0q(a+2)+B0q(a+2); stage B1(b+2)
    if (it + 1 < NITER) {
      READ_A(aF0, 0, 0);
      READ_B(bF0, 0, 0);
    }
    STAGE(Bp, bcol, b + 2, 1, 1);
    MM(1, 1, aF1, bF1);
    GATE8(); BAR();
  }

  // Epilogue: s = (x_sq - 2*dot) + w_sq (reference fp32 rounding order).
  // C/D 16x16x32: col = lane&15, row = (lane>>4)*4 + reg.
  // acc[i][j]: i = mh*4+m_, j = nh*2+n_;
  // row = brow + mh*128 + wm*64 + m_*16 + q*4 + r
  // col = bcol + nh*128 + wn*32 + n_*16 + cc
#pragma unroll
  for (int i = 0; i < 8; ++i) {
    const int mh = i >> 2, m_ = i & 3;
#pragma unroll
    for (int r = 0; r < 4; ++r) {
      const int row = brow + mh * 128 + wm * 64 + m_ * 16 + q * 4 + r;
      const float xs = xsq[row];
      unsigned long long best = ~0ULL;
#pragma unroll
      for (int j = 0; j < 4; ++j) {
        const int nh = j >> 1, n_ = j & 1;
        const int col = bcol + nh * 128 + wn * 32 + n_ * 16 + cc;
        const float s = (xs - 2.0f * acc[i][j][r]) + wsq[col];
        unsigned ub = __float_as_uint(s);
        ub = (ub & 0x80000000u) ? ~ub : (ub | 0x80000000u);
        const unsigned long long key =
            ((unsigned long long)ub << 32) | (unsigned)col;
        if (key < best) best = key;
      }
#pragma unroll
      for (int o = 1; o < 16; o <<= 1) {
        const unsigned long long v = __shfl_xor(best, o);
        if (v < best) best = v;
      }
      if (cc == 0) atomicMin(&keys[row], best);
    }
  }
}

// ---- transpose G [O,H] -> GT [H,O] ----
__global__ __launch_bounds__(256) void transposeG_kernel(
    const float* __restrict__ G, float* __restrict__ GT)
{
  __shared__ float tile[32][33];
  const int h0 = blockIdx.x * 32;
  const int o0 = blockIdx.y * 32;
  const int tx = threadIdx.x;
  const int ty = threadIdx.y;
#pragma unroll
  for (int j = 0; j < 4; ++j) {
    const int o = o0 + ty + j * 8;
    if (o < O_) tile[ty + j * 8][tx] = G[(size_t)o * H_ + h0 + tx];
  }
  __syncthreads();
  const int o = o0 + tx;
  if (o < O_) {
#pragma unroll
    for (int j = 0; j < 4; ++j)
      GT[(size_t)(h0 + ty + j * 8) * O_ + o] = tile[tx][ty + j * 8];
  }
}

// ---- winners + row gather ----
__global__ __launch_bounds__(256) void finalize_kernel(
    const unsigned long long* __restrict__ keys,
    const float* __restrict__ GT, float* __restrict__ out)
{
  const int b = blockIdx.x;
  const unsigned w = (unsigned)(keys[b] & 0xFFFFFFFFull);
  if (threadIdx.x == 0) out[(size_t)B_ * O_ + b] = (float)w;
  const float4* src = (const float4*)(GT + (size_t)w * O_);
  float4* dst = (float4*)(out + (size_t)b * O_);
  for (int i = threadIdx.x; i < O_ / 4; i += 256) dst[i] = src[i];
}

extern "C" void kernel_launch(void* const* d_in, const int* in_sizes, int n_in,
                              void* d_out, int out_size, void* d_ws, size_t ws_size,
                              hipStream_t stream)
{
  (void)in_sizes; (void)n_in; (void)out_size; (void)ws_size;
  const float* x = (const float*)d_in[0];
  const float* kw = (const float*)d_in[1];
  const float* gw = (const float*)d_in[2];
  float* out = (float*)d_out;

  char* ws = (char*)d_ws;
  // A' 16.78MB | B' 33.55MB | xsq 16KB | wsq 32KB | keys 32KB ; GT overlays A'/B'
  __hip_bfloat16* Ap = (__hip_bfloat16*)(ws);
  __hip_bfloat16* Bp = (__hip_bfloat16*)(ws + 16777216);
  float* xsq = (float*)(ws + 50331648);
  float* wsq = (float*)(ws + 50331648 + 16384);
  unsigned long long* keys = (unsigned long long*)(ws + 50331648 + 16384 + 32768);
  float* GT = (float*)(ws);  // dead A'/B' space after GEMM

  split_all_kernel<<<B_ + H_, 256, 0, stream>>>(x, kw, Ap, Bp, xsq, wsq, keys);
  gemm_argmin_kernel<<<512, 512, 0, stream>>>(Ap, Bp, xsq, wsq, keys);
  transposeG_kernel<<<dim3(H_ / 32, (O_ + 31) / 32), dim3(32, 8), 0, stream>>>(gw, GT);
  finalize_kernel<<<B_, 256, 0, stream>>>(keys, GT, out);
}

// Round 7
// 243.537 us; speedup vs baseline: 1.1530x; 1.1530x over previous
//
#include <hip/hip_runtime.h>
#include <hip/hip_bf16.h>

#define B_ 4096
#define D_ 1024
#define H_ 8192
#define O_ 1000
#define K2 2048          // physical packed K ([hi|lo])
#define NT 48            // logical K-tiles: 3072 / 64
#define NITER (NT / 2)

typedef __attribute__((ext_vector_type(8))) short short8;
typedef __attribute__((ext_vector_type(4))) short short4v;
typedef __attribute__((ext_vector_type(4))) float f32x4;

union BF4 { __hip_bfloat16 b[4]; short4v s; };

__device__ __forceinline__ void gload16(void* ldsp, const void* g) {
  __builtin_amdgcn_global_load_lds(
      (const __attribute__((address_space(1))) unsigned int*)g,
      (__attribute__((address_space(3))) unsigned int*)ldsp, 16, 0, 0);
}

// K-tile T -> column offset in packed [hi(0..1023)|lo(1024..2047)] rows.
// Interleaved bf16x3: T = 3t+r: r0 = xh*wh, r1 = xl*wh, r2 = xh*wl.
__device__ __forceinline__ int aoff_(int T) {
  const int t = T / 3, r = T - 3 * t;
  return (r == 1 ? 1024 : 0) + t * 64;
}
__device__ __forceinline__ int boff_(int T) {
  const int t = T / 3, r = T - 3 * t;
  return (r == 2 ? 1024 : 0) + t * 64;
}

// ---- merged split: fp32 -> [hi|lo] bf16 + sum-of-squares + keys init ----
__global__ __launch_bounds__(256) void split_all_kernel(
    const float* __restrict__ x, const float* __restrict__ w,
    __hip_bfloat16* __restrict__ Ap, __hip_bfloat16* __restrict__ Bp,
    float* __restrict__ xsq, float* __restrict__ wsq,
    unsigned long long* __restrict__ keys)
{
  const int r = blockIdx.x;
  const int t = threadIdx.x;
  const float* src;
  __hip_bfloat16* dst;
  float* sq;
  if (r < B_) {
    src = x + (size_t)r * D_; dst = Ap + (size_t)r * K2; sq = xsq + r;
    if (t == 0) keys[r] = ~0ULL;
  } else {
    const int rr = r - B_;
    src = w + (size_t)rr * D_; dst = Bp + (size_t)rr * K2; sq = wsq + rr;
  }
  const float4 v = ((const float4*)src)[t];
  float ss = v.x * v.x + v.y * v.y + v.z * v.z + v.w * v.w;

  BF4 Hh, Ll;
  const float e[4] = {v.x, v.y, v.z, v.w};
#pragma unroll
  for (int i = 0; i < 4; ++i) {
    __hip_bfloat16 h = __float2bfloat16(e[i]);
    Hh.b[i] = h;
    Ll.b[i] = __float2bfloat16(e[i] - __bfloat162float(h));
  }
  *(short4v*)(dst + t * 4) = Hh.s;
  *(short4v*)(dst + 1024 + t * 4) = Ll.s;

#pragma unroll
  for (int o = 32; o > 0; o >>= 1) ss += __shfl_down(ss, o);
  __shared__ float wsum[4];
  if ((t & 63) == 0) wsum[t >> 6] = ss;
  __syncthreads();
  if (t == 0) *sq = (wsum[0] + wsum[1]) + (wsum[2] + wsum[3]);
}

// ---- 256x256 GEMM, m201-style 8-phase (2 tiles/iter), 2 barriers/phase ----
// LDS regions per dbuf d: A0@d+0 (rows 0-127), A1@d+16K (128-255),
// B0@d+32K (cols 0-127), B1@d+48K (128-255). 128B rows;
// phys 16B-unit = logical ^ (row&7) via pre-swizzled global source.
// INTERLEAVED wave mapping: wave wm owns rows {mq*128 + wm*64 ..+64} ->
// quadrant (mq,nq) reads exactly ONE A-region and ONE B-region.
// Snake order per tile: (0,0) (0,1) (1,1) (1,0): reads 12/4/8/0 b128,
// live set 16 b128. Stage 1 half/phase, lead 5-7 phases:
//   ph0:A1(b) ph1:A0(a+2) ph2:B0(a+2) ph3:B1(a+2)
//   ph4:A1(a+2) ph5:A0(b+2) ph6:B0(b+2) ph7:B1(b+2)
// Gates (steady): ph0-end vmcnt(8) [drains B1(a),A1(a)], ph3-end vmcnt(10)
// [A0(b),B0(b)], ph4-end vmcnt(8) [B1(b),A1(b)], ph7-end vmcnt(10)
// [A0(a+2),B0(a+2)].  Last iter (stages guarded off): ph3->4, ph4->0.

#define BAR() do { asm volatile("" ::: "memory"); \
                   __builtin_amdgcn_s_barrier(); \
                   asm volatile("" ::: "memory"); } while (0)
#define GATEN(n) asm volatile("s_waitcnt vmcnt(" #n ")" ::: "memory")

#define STAGE(P, prow, T, isB, h) do { if ((T) < NT) { \
    const int koff_ = (isB) ? boff_(T) : aoff_(T); \
    const __hip_bfloat16* s_ = (P) + (size_t)((prow) + (h)*128 + wid*16 + srow) * K2 + koff_ + sunit * 8; \
    char* d_ = lds + ((T)&1)*65536 + (isB)*32768 + (h)*16384 + wid*2048 + lane*16; \
    gload16(d_, s_); gload16(d_ + 1024, s_ + 8*K2); } } while (0)

// 8 reads: A-frags of region mh (4 m x 2 kk), wave's 64-row slice
#define READ_A(dst, db, mh) do { \
    const char* p_ = lds + (db) + (mh)*16384 + (wm*64 + cc)*128; \
    _Pragma("unroll") for (int m_ = 0; m_ < 4; ++m_) { \
      dst[2*m_]   = *(const short8*)(p_ + m_*2048 + kof0); \
      dst[2*m_+1] = *(const short8*)(p_ + m_*2048 + kof1); } } while (0)

// 4 reads: B-frags of region nh (2 n x 2 kk), wave's 32-col slice
#define READ_B(dst, db, nh) do { \
    const char* p_ = lds + (db) + 32768 + (nh)*16384 + (wn*32 + cc)*128; \
    _Pragma("unroll") for (int n_ = 0; n_ < 2; ++n_) { \
      dst[2*n_]   = *(const short8*)(p_ + n_*2048 + kof0); \
      dst[2*n_+1] = *(const short8*)(p_ + n_*2048 + kof1); } } while (0)

#define MM(mh, nh, AF, BF) do { \
    __builtin_amdgcn_s_setprio(1); \
    _Pragma("unroll") for (int m_ = 0; m_ < 4; ++m_) \
    _Pragma("unroll") for (int n_ = 0; n_ < 2; ++n_) \
    _Pragma("unroll") for (int kk = 0; kk < 2; ++kk) \
      acc[(mh)*4+m_][(nh)*2+n_] = __builtin_amdgcn_mfma_f32_16x16x32_bf16( \
          AF[2*m_+kk], BF[2*n_+kk], acc[(mh)*4+m_][(nh)*2+n_], 0, 0, 0); \
    __builtin_amdgcn_s_setprio(0); } while (0)

__global__ __launch_bounds__(512, 2) void gemm_argmin_kernel(
    const __hip_bfloat16* __restrict__ Ap, const __hip_bfloat16* __restrict__ Bp,
    const float* __restrict__ xsq, const float* __restrict__ wsq,
    unsigned long long* __restrict__ keys)
{
  __shared__ char lds[131072];

  const int t = threadIdx.x;
  // XCD-aware: square 8x8 tile-chunk per XCD (r4-proven).
  const int id = blockIdx.x;
  const int xcd = id & 7;
  const int r_ = id >> 3;
  const int by = (xcd >> 2) * 8 + (r_ >> 3);
  const int bx = (xcd & 3) * 8 + (r_ & 7);
  const int brow = by * 256, bcol = bx * 256;

  const int lane = t & 63, wid = t >> 6;
  const int wm = wid >> 2, wn = wid & 3;
  const int cc = lane & 15, q = lane >> 4, sw = lane & 7;
  const int kof0 = (q ^ sw) * 16;
  const int kof1 = ((4 + q) ^ sw) * 16;

  const int srow = lane >> 3;
  const int sunit = (lane & 7) ^ srow;

  f32x4 acc[8][4] = {};
  short8 aF[8], bF0[4], bF1[4];

  // Prologue (load order = steady-state seed):
  // A0(0) B0(0) B1(0) A1(0) A0(1) B0(1) B1(1) -> vmcnt(10) drains A0(0),B0(0)
  STAGE(Ap, brow, 0, 0, 0);
  STAGE(Bp, bcol, 0, 1, 0);
  STAGE(Bp, bcol, 0, 1, 1);
  STAGE(Ap, brow, 0, 0, 1);
  STAGE(Ap, brow, 1, 0, 0);
  STAGE(Bp, bcol, 1, 1, 0);
  STAGE(Bp, bcol, 1, 1, 1);
  GATEN(10);
  BAR();

  for (int it = 0; it < NITER; ++it) {
    const int a = 2 * it, b = a + 1;
    const bool lastit = (it == NITER - 1);
    // ======== tile a (dbuf0) ========
    // ph0: q(0,0); reads A0+B0 (12); stage A1(b)
    READ_A(aF, 0, 0);
    READ_B(bF0, 0, 0);
    STAGE(Ap, brow, b, 0, 1);
    BAR();
    MM(0, 0, aF, bF0);
    GATEN(8);
    BAR();
    // ph1: q(0,1); reads B1 (4); stage A0(a+2)
    READ_B(bF1, 0, 1);
    STAGE(Ap, brow, a + 2, 0, 0);
    BAR();
    MM(0, 1, aF, bF1);
    BAR();
    // ph2: q(1,1); reads A1 (8); stage B0(a+2)
    READ_A(aF, 0, 1);
    STAGE(Bp, bcol, a + 2, 1, 0);
    BAR();
    MM(1, 1, aF, bF1);
    BAR();
    // ph3: q(1,0); no reads (bF0 held); stage B1(a+2)
    STAGE(Bp, bcol, a + 2, 1, 1);
    BAR();
    MM(1, 0, aF, bF0);
    if (lastit) { GATEN(4); } else { GATEN(10); }
    BAR();
    // ======== tile b (dbuf1) ========
    // ph4: q(0,0); reads A0+B0; stage A1(a+2)
    READ_A(aF, 65536, 0);
    READ_B(bF0, 65536, 0);
    STAGE(Ap, brow, a + 2, 0, 1);
    BAR();
    MM(0, 0, aF, bF0);
    if (lastit) { GATEN(0); } else { GATEN(8); }
    BAR();
    // ph5: q(0,1); reads B1; stage A0(b+2)
    READ_B(bF1, 65536, 1);
    STAGE(Ap, brow, b + 2, 0, 0);
    BAR();
    MM(0, 1, aF, bF1);
    BAR();
    // ph6: q(1,1); reads A1; stage B0(b+2)
    READ_A(aF, 65536, 1);
    STAGE(Bp, bcol, b + 2, 1, 0);
    BAR();
    MM(1, 1, aF, bF1);
    BAR();
    // ph7: q(1,0); no reads; stage B1(b+2)
    STAGE(Bp, bcol, b + 2, 1, 1);
    BAR();
    MM(1, 0, aF, bF0);
    GATEN(10);
    BAR();
  }

  // Epilogue: s = (x_sq - 2*dot) + w_sq (reference fp32 rounding order).
  // C/D 16x16x32: col = lane&15, row = (lane>>4)*4 + reg.
  // acc[i][j]: i = mq*4+m_, j = nq*2+n_ with INTERLEAVED wave mapping:
  // row = brow + mq*128 + wm*64 + m_*16 + q*4 + r
  // col = bcol + nq*128 + wn*32 + n_*16 + cc        (r6-verified)
#pragma unroll
  for (int i = 0; i < 8; ++i) {
    const int mh = i >> 2, m_ = i & 3;
#pragma unroll
    for (int r = 0; r < 4; ++r) {
      const int row = brow + mh * 128 + wm * 64 + m_ * 16 + q * 4 + r;
      const float xs = xsq[row];
      unsigned long long best = ~0ULL;
#pragma unroll
      for (int j = 0; j < 4; ++j) {
        const int nh = j >> 1, n_ = j & 1;
        const int col = bcol + nh * 128 + wn * 32 + n_ * 16 + cc;
        const float s = (xs - 2.0f * acc[i][j][r]) + wsq[col];
        unsigned ub = __float_as_uint(s);
        ub = (ub & 0x80000000u) ? ~ub : (ub | 0x80000000u);
        const unsigned long long key =
            ((unsigned long long)ub << 32) | (unsigned)col;
        if (key < best) best = key;
      }
#pragma unroll
      for (int o = 1; o < 16; o <<= 1) {
        const unsigned long long v = __shfl_xor(best, o);
        if (v < best) best = v;
      }
      if (cc == 0) atomicMin(&keys[row], best);
    }
  }
}

// ---- transpose G [O,H] -> GT [H,O] ----
__global__ __launch_bounds__(256) void transposeG_kernel(
    const float* __restrict__ G, float* __restrict__ GT)
{
  __shared__ float tile[32][33];
  const int h0 = blockIdx.x * 32;
  const int o0 = blockIdx.y * 32;
  const int tx = threadIdx.x;
  const int ty = threadIdx.y;
#pragma unroll
  for (int j = 0; j < 4; ++j) {
    const int o = o0 + ty + j * 8;
    if (o < O_) tile[ty + j * 8][tx] = G[(size_t)o * H_ + h0 + tx];
  }
  __syncthreads();
  const int o = o0 + tx;
  if (o < O_) {
#pragma unroll
    for (int j = 0; j < 4; ++j)
      GT[(size_t)(h0 + ty + j * 8) * O_ + o] = tile[tx][ty + j * 8];
  }
}

// ---- winners + row gather ----
__global__ __launch_bounds__(256) void finalize_kernel(
    const unsigned long long* __restrict__ keys,
    const float* __restrict__ GT, float* __restrict__ out)
{
  const int b = blockIdx.x;
  const unsigned w = (unsigned)(keys[b] & 0xFFFFFFFFull);
  if (threadIdx.x == 0) out[(size_t)B_ * O_ + b] = (float)w;
  const float4* src = (const float4*)(GT + (size_t)w * O_);
  float4* dst = (float4*)(out + (size_t)b * O_);
  for (int i = threadIdx.x; i < O_ / 4; i += 256) dst[i] = src[i];
}

extern "C" void kernel_launch(void* const* d_in, const int* in_sizes, int n_in,
                              void* d_out, int out_size, void* d_ws, size_t ws_size,
                              hipStream_t stream)
{
  (void)in_sizes; (void)n_in; (void)out_size; (void)ws_size;
  const float* x = (const float*)d_in[0];
  const float* kw = (const float*)d_in[1];
  const float* gw = (const float*)d_in[2];
  float* out = (float*)d_out;

  char* ws = (char*)d_ws;
  // A' 16.78MB | B' 33.55MB | xsq 16KB | wsq 32KB | keys 32KB ; GT overlays A'/B'
  __hip_bfloat16* Ap = (__hip_bfloat16*)(ws);
  __hip_bfloat16* Bp = (__hip_bfloat16*)(ws + 16777216);
  float* xsq = (float*)(ws + 50331648);
  float* wsq = (float*)(ws + 50331648 + 16384);
  unsigned long long* keys = (unsigned long long*)(ws + 50331648 + 16384 + 32768);
  float* GT = (float*)(ws);  // dead A'/B' space after GEMM

  split_all_kernel<<<B_ + H_, 256, 0, stream>>>(x, kw, Ap, Bp, xsq, wsq, keys);
  gemm_argmin_kernel<<<512, 512, 0, stream>>>(Ap, Bp, xsq, wsq, keys);
  transposeG_kernel<<<dim3(H_ / 32, (O_ + 31) / 32), dim3(32, 8), 0, stream>>>(gw, GT);
  finalize_kernel<<<B_, 256, 0, stream>>>(keys, GT, out);
}

// Round 8
// 242.621 us; speedup vs baseline: 1.1573x; 1.0038x over previous
//
#include <hip/hip_runtime.h>
#include <hip/hip_bf16.h>

#define B_ 4096
#define D_ 1024
#define H_ 8192
#define O_ 1000
#define K2 2048          // physical packed K ([hi|lo])
#define NT 48            // logical K-tiles: 3072 / 64
#define NITER (NT / 2)

typedef __attribute__((ext_vector_type(8))) short short8;
typedef __attribute__((ext_vector_type(4))) short short4v;
typedef __attribute__((ext_vector_type(4))) float f32x4;

union BF4 { __hip_bfloat16 b[4]; short4v s; };

__device__ __forceinline__ void gload16(void* ldsp, const void* g) {
  __builtin_amdgcn_global_load_lds(
      (const __attribute__((address_space(1))) unsigned int*)g,
      (__attribute__((address_space(3))) unsigned int*)ldsp, 16, 0, 0);
}

// K-tile T -> column offset in packed [hi|lo] rows. bf16x3 interleave:
// T = 3t+r: r0 = xh*wh, r1 = xl*wh, r2 = xh*wl.
__device__ __forceinline__ int aoff_(int T) {
  const int t = T / 3, r = T - 3 * t;
  return (r == 1 ? 1024 : 0) + t * 64;
}
__device__ __forceinline__ int boff_(int T) {
  const int t = T / 3, r = T - 3 * t;
  return (r == 2 ? 1024 : 0) + t * 64;
}

// ---- merged split: fp32 -> [hi|lo] bf16 + sum-of-squares + keys init ----
__global__ __launch_bounds__(256) void split_all_kernel(
    const float* __restrict__ x, const float* __restrict__ w,
    __hip_bfloat16* __restrict__ Ap, __hip_bfloat16* __restrict__ Bp,
    float* __restrict__ xsq, float* __restrict__ wsq,
    unsigned long long* __restrict__ keys)
{
  const int r = blockIdx.x;
  const int t = threadIdx.x;
  const float* src;
  __hip_bfloat16* dst;
  float* sq;
  if (r < B_) {
    src = x + (size_t)r * D_; dst = Ap + (size_t)r * K2; sq = xsq + r;
    if (t == 0) keys[r] = ~0ULL;
  } else {
    const int rr = r - B_;
    src = w + (size_t)rr * D_; dst = Bp + (size_t)rr * K2; sq = wsq + rr;
  }
  const float4 v = ((const float4*)src)[t];
  float ss = v.x * v.x + v.y * v.y + v.z * v.z + v.w * v.w;

  BF4 Hh, Ll;
  const float e[4] = {v.x, v.y, v.z, v.w};
#pragma unroll
  for (int i = 0; i < 4; ++i) {
    __hip_bfloat16 h = __float2bfloat16(e[i]);
    Hh.b[i] = h;
    Ll.b[i] = __float2bfloat16(e[i] - __bfloat162float(h));
  }
  *(short4v*)(dst + t * 4) = Hh.s;
  *(short4v*)(dst + 1024 + t * 4) = Ll.s;

#pragma unroll
  for (int o = 32; o > 0; o >>= 1) ss += __shfl_down(ss, o);
  __shared__ float wsum[4];
  if ((t & 63) == 0) wsum[t >> 6] = ss;
  __syncthreads();
  if (t == 0) *sq = (wsum[0] + wsum[1]) + (wsum[2] + wsum[3]);
}

// ---- 256x256 GEMM: uniform phases, asm ds_read + counted lgkm overlap ----
// LDS dbuf d: A0@d+0, A1@d+16K, B0@d+32K, B1@d+48K; 128B rows; phys 16B-unit
// = logical ^ (row&7) via pre-swizzled global source.
// Phase(mh,kk): 16 MFMA on regs read LAST phase; issues 8 asm ds_reads for
// NEXT phase (4 A at (mh',kk') + 4 B at kk', B re-read per phase).
// Phase order per tile: (0,k0) (0,k1) (1,k0) (1,k1) — consumed sets ping-pong.
// lgkmcnt(8) before each cluster = the 8 just-issued stay in flight.
// Stage schedule (1 half/phase): T.ph0: T+1.B1; ph1: T+1.A0; ph2: T+1.A1;
// ph3: T+2.B0 (after LGKM: same-dbuf WAR safety).
// Gates: T.ph1 vmcnt(4) [drains T.A1]; T.ph3 vmcnt(2) [drains T+1.B0,B1,A0].
// Barriers ONLY at the two gates (2/tile).

#define BAR() do { asm volatile("" ::: "memory"); \
                   __builtin_amdgcn_s_barrier(); \
                   asm volatile("" ::: "memory"); } while (0)
#define SB0() __builtin_amdgcn_sched_barrier(0)
#define GATE_S(S) asm volatile("s_waitcnt vmcnt(" S ")")
#define LGKM8() do { asm volatile("s_waitcnt lgkmcnt(8)"); SB0(); } while (0)
#define LGKM0() do { asm volatile("s_waitcnt lgkmcnt(0)"); SB0(); } while (0)

#define DSR(dst, base, OFF) \
  asm volatile("ds_read_b128 %0, %1 offset:" OFF : "=v"(dst) : "v"(base))

#define RD4A(arr, base) do { unsigned _ba = (base); \
  DSR(arr[0], _ba, "0");    DSR(arr[1], _ba, "2048"); \
  DSR(arr[2], _ba, "4096"); DSR(arr[3], _ba, "6144"); } while (0)
#define RD4B(arr, base) do { unsigned _bb = (base); \
  DSR(arr[0], _bb, "0");     DSR(arr[1], _bb, "2048"); \
  DSR(arr[2], _bb, "16384"); DSR(arr[3], _bb, "18432"); } while (0)

#define STAGE(P, prow, T, isB, h) do { if ((T) < NT) { \
    const int koff_ = (isB) ? boff_(T) : aoff_(T); \
    const __hip_bfloat16* s_ = (P) + (size_t)((prow) + (h)*128 + wid*16 + srow) * K2 + koff_ + sunit * 8; \
    char* d_ = lds + ((T)&1)*65536 + (isB)*32768 + (h)*16384 + wid*2048 + lane*16; \
    gload16(d_, s_); gload16(d_ + 1024, s_ + 8*K2); } } while (0)

#define MMQ(mh, A, B) do { \
    __builtin_amdgcn_s_setprio(1); \
    _Pragma("unroll") for (int m_ = 0; m_ < 4; ++m_) \
    _Pragma("unroll") for (int n_ = 0; n_ < 4; ++n_) \
      acc[(mh)*4+m_][n_] = __builtin_amdgcn_mfma_f32_16x16x32_bf16( \
          A[m_], B[n_], acc[(mh)*4+m_][n_], 0, 0, 0); \
    __builtin_amdgcn_s_setprio(0); \
    SB0(); } while (0)

// One tile = 4 phases. DS = this tile's dbuf sel (0/65536). TT = tile index.
// G1 = ph1 gate count string. RDN = issue next-tile reads at ph3 (0 on last).
#define TILE4(DS, TT, G1, RDN) do { \
    /* ph0: MFMA(mh0,k0); reads (mh0,k1); stage T+1.B1 */ \
    RD4A(s1A, aB01 + (DS)); \
    RD4B(s1B, bB1  + (DS)); \
    STAGE(Bp, bcol, (TT) + 1, 1, 1); \
    LGKM8(); \
    MMQ(0, s0A, s0B); \
    /* ph1: gate T.A1; MFMA(mh0,k1); reads (mh1,k0); stage T+1.A0 */ \
    GATE_S(G1); BAR(); \
    RD4A(s0A, aB10 + (DS)); \
    RD4B(s0B, bB0  + (DS)); \
    STAGE(Ap, brow, (TT) + 1, 0, 0); \
    LGKM8(); \
    MMQ(0, s1A, s1B); \
    /* ph2: MFMA(mh1,k0); reads (mh1,k1); stage T+1.A1 */ \
    RD4A(s1A, aB11 + (DS)); \
    RD4B(s1B, bB1  + (DS)); \
    STAGE(Ap, brow, (TT) + 1, 0, 1); \
    LGKM8(); \
    MMQ(1, s0A, s0B); \
    /* ph3: gate next tile; MFMA(mh1,k1); reads next (mh0,k0); stage T+2.B0 */ \
    GATE_S("2"); BAR(); \
    if (RDN) { \
      RD4A(s0A, aB00 + ((DS) ^ 65536)); \
      RD4B(s0B, bB0  + ((DS) ^ 65536)); \
      LGKM8(); \
    } else { LGKM0(); } \
    STAGE(Bp, bcol, (TT) + 2, 1, 0); \
    MMQ(1, s1A, s1B); \
  } while (0)

__global__ __launch_bounds__(512, 2) void gemm_argmin_kernel(
    const __hip_bfloat16* __restrict__ Ap, const __hip_bfloat16* __restrict__ Bp,
    const float* __restrict__ xsq, const float* __restrict__ wsq,
    unsigned long long* __restrict__ keys)
{
  __shared__ char lds[131072];

  const int t = threadIdx.x;
  // XCD-aware: square 8x8 tile-chunk per XCD (r4-proven).
  const int id = blockIdx.x;
  const int xcd = id & 7;
  const int r_ = id >> 3;
  const int by = (xcd >> 2) * 8 + (r_ >> 3);
  const int bx = (xcd & 3) * 8 + (r_ & 7);
  const int brow = by * 256, bcol = bx * 256;

  const int lane = t & 63, wid = t >> 6;
  const int wm = wid >> 2, wn = wid & 3;
  const int cc = lane & 15, q = lane >> 4, sw = lane & 7;
  const int kof0 = (q ^ sw) * 16;
  const int kof1 = ((4 + q) ^ sw) * 16;

  const int srow = lane >> 3;
  const int sunit = (lane & 7) ^ srow;

  // asm ds_read base addresses (dbuf0; +65536 selects dbuf1)
  const unsigned lb = (unsigned)(uintptr_t)lds;
  const unsigned aRow = (unsigned)((wm * 64 + cc) * 128);
  const unsigned bRow = (unsigned)(32768 + (wn * 32 + cc) * 128);
  const unsigned aB00 = lb + aRow + kof0;
  const unsigned aB01 = lb + aRow + kof1;
  const unsigned aB10 = lb + 16384 + aRow + kof0;
  const unsigned aB11 = lb + 16384 + aRow + kof1;
  const unsigned bB0 = lb + bRow + kof0;
  const unsigned bB1 = lb + bRow + kof1;

  f32x4 acc[8][4] = {};
  short8 s0A[4], s0B[4], s1A[4], s1B[4];

  // Prologue (FIFO: T0.B0 T0.B1 T0.A0 T0.A1 T1.B0), gate leaves {T0.A1,T1.B0}
  STAGE(Bp, bcol, 0, 1, 0);
  STAGE(Bp, bcol, 0, 1, 1);
  STAGE(Ap, brow, 0, 0, 0);
  STAGE(Ap, brow, 0, 0, 1);
  STAGE(Bp, bcol, 1, 1, 0);
  GATE_S("4");
  BAR();
  RD4A(s0A, aB00);   // tile0 (mh0,k0) operands
  RD4B(s0B, bB0);
  SB0();

  for (int it = 0; it < NITER - 1; ++it) {
    const int a = 2 * it;
    TILE4(0,     a,     "4", 1);
    TILE4(65536, a + 1, "4", 1);
  }
  {
    const int a = 2 * (NITER - 1);
    TILE4(0,     a,     "4", 1);
    TILE4(65536, a + 1, "0", 0);   // last tile: drain-gate, no next reads
  }

  // Epilogue: s = (x_sq - 2*dot) + w_sq (reference fp32 rounding order).
  // C/D 16x16x32: col = lane&15, row = (lane>>4)*4 + reg.
  // row = brow + mh*128 + wm*64 + m_*16 + q*4 + r
  // col = bcol + (j>>1)*128 + wn*32 + (j&1)*16 + cc   (r6/r7-verified)
#pragma unroll
  for (int i = 0; i < 8; ++i) {
    const int mh = i >> 2, m_ = i & 3;
#pragma unroll
    for (int r = 0; r < 4; ++r) {
      const int row = brow + mh * 128 + wm * 64 + m_ * 16 + q * 4 + r;
      const float xs = xsq[row];
      unsigned long long best = ~0ULL;
#pragma unroll
      for (int j = 0; j < 4; ++j) {
        const int col = bcol + (j >> 1) * 128 + wn * 32 + (j & 1) * 16 + cc;
        const float s = (xs - 2.0f * acc[i][j][r]) + wsq[col];
        unsigned ub = __float_as_uint(s);
        ub = (ub & 0x80000000u) ? ~ub : (ub | 0x80000000u);
        const unsigned long long key =
            ((unsigned long long)ub << 32) | (unsigned)col;
        if (key < best) best = key;
      }
#pragma unroll
      for (int o = 1; o < 16; o <<= 1) {
        const unsigned long long v = __shfl_xor(best, o);
        if (v < best) best = v;
      }
      if (cc == 0) atomicMin(&keys[row], best);
    }
  }
}

// ---- transpose G [O,H] -> GT [H,O] ----
__global__ __launch_bounds__(256) void transposeG_kernel(
    const float* __restrict__ G, float* __restrict__ GT)
{
  __shared__ float tile[32][33];
  const int h0 = blockIdx.x * 32;
  const int o0 = blockIdx.y * 32;
  const int tx = threadIdx.x;
  const int ty = threadIdx.y;
#pragma unroll
  for (int j = 0; j < 4; ++j) {
    const int o = o0 + ty + j * 8;
    if (o < O_) tile[ty + j * 8][tx] = G[(size_t)o * H_ + h0 + tx];
  }
  __syncthreads();
  const int o = o0 + tx;
  if (o < O_) {
#pragma unroll
    for (int j = 0; j < 4; ++j)
      GT[(size_t)(h0 + ty + j * 8) * O_ + o] = tile[tx][ty + j * 8];
  }
}

// ---- winners + row gather ----
__global__ __launch_bounds__(256) void finalize_kernel(
    const unsigned long long* __restrict__ keys,
    const float* __restrict__ GT, float* __restrict__ out)
{
  const int b = blockIdx.x;
  const unsigned w = (unsigned)(keys[b] & 0xFFFFFFFFull);
  if (threadIdx.x == 0) out[(size_t)B_ * O_ + b] = (float)w;
  const float4* src = (const float4*)(GT + (size_t)w * O_);
  float4* dst = (float4*)(out + (size_t)b * O_);
  for (int i = threadIdx.x; i < O_ / 4; i += 256) dst[i] = src[i];
}

extern "C" void kernel_launch(void* const* d_in, const int* in_sizes, int n_in,
                              void* d_out, int out_size, void* d_ws, size_t ws_size,
                              hipStream_t stream)
{
  (void)in_sizes; (void)n_in; (void)out_size; (void)ws_size;
  const float* x = (const float*)d_in[0];
  const float* kw = (const float*)d_in[1];
  const float* gw = (const float*)d_in[2];
  float* out = (float*)d_out;

  char* ws = (char*)d_ws;
  // A' 16.78MB | B' 33.55MB | xsq 16KB | wsq 32KB | keys 32KB ; GT overlays A'/B'
  __hip_bfloat16* Ap = (__hip_bfloat16*)(ws);
  __hip_bfloat16* Bp = (__hip_bfloat16*)(ws + 16777216);
  float* xsq = (float*)(ws + 50331648);
  float* wsq = (float*)(ws + 50331648 + 16384);
  unsigned long long* keys = (unsigned long long*)(ws + 50331648 + 16384 + 32768);
  float* GT = (float*)(ws);  // dead A'/B' space after GEMM

  split_all_kernel<<<B_ + H_, 256, 0, stream>>>(x, kw, Ap, Bp, xsq, wsq, keys);
  gemm_argmin_kernel<<<512, 512, 0, stream>>>(Ap, Bp, xsq, wsq, keys);
  transposeG_kernel<<<dim3(H_ / 32, (O_ + 31) / 32), dim3(32, 8), 0, stream>>>(gw, GT);
  finalize_kernel<<<B_, 256, 0, stream>>>(keys, GT, out);
}